// Round 3
// baseline (386.838 us; speedup 1.0000x reference)
//
#include <hip/hip_runtime.h>
#include <hip/hip_cooperative_groups.h>
#include <math.h>

namespace cg = cooperative_groups;

#define DEV __device__ __forceinline__

namespace {

struct C2 { float x, y; };

// ---------------- workspace layout (float offsets) ----------------
constexpr size_t OFF_NRM  = 163988;   // 32
constexpr size_t OFF_MONO = 164096;   // 32*1024*float2 = 65536
constexpr size_t OFF_ACC  = 229632;   // 65536
constexpr size_t OFF_ST   = 295168;   // 1024*1024*float2 = 2097152
constexpr size_t OFF_EV   = 2392320;  // 32*30
constexpr size_t OFF_H    = 2393280;  // 32*512

// ---------------- gate primitives ----------------
// amplitude index i = (reg<<6) | lane ; wire w lives at bit position P = 9 - w.

template<int P>
DEV void ry_gate(C2 v[16], int lane, float c, float s) {
  if constexpr (P >= 6) {
    constexpr int rm = 1 << (P - 6);
#pragma unroll
    for (int r = 0; r < 16; ++r) {
      if ((r & rm) == 0) {
        C2 a = v[r], b = v[r | rm];
        v[r].x      = fmaf(c, a.x, -s * b.x);
        v[r].y      = fmaf(c, a.y, -s * b.y);
        v[r | rm].x = fmaf(s, a.x,  c * b.x);
        v[r | rm].y = fmaf(s, a.y,  c * b.y);
      }
    }
  } else {
    constexpr int lm = 1 << P;
    float sg = (lane & lm) ? s : -s;
#pragma unroll
    for (int r = 0; r < 16; ++r) {
      float px = __shfl_xor(v[r].x, lm, 64);
      float py = __shfl_xor(v[r].y, lm, 64);
      v[r].x = fmaf(c, v[r].x, sg * px);
      v[r].y = fmaf(c, v[r].y, sg * py);
    }
  }
}

template<int PC, int PT>
DEV void crx_gate(C2 v[16], int lane, float c, float s) {
  if constexpr (PT >= 6) {
    constexpr int tm = 1 << (PT - 6);
#pragma unroll
    for (int r = 0; r < 16; ++r) {
      if ((r & tm) == 0) {
        if constexpr (PC >= 6) {
          constexpr int cm = 1 << (PC - 6);
          if ((r & cm) != 0) {
            C2 a = v[r], b = v[r | tm];
            v[r].x      = fmaf(c, a.x,  s * b.y);
            v[r].y      = fmaf(c, a.y, -s * b.x);
            v[r | tm].x = fmaf(c, b.x,  s * a.y);
            v[r | tm].y = fmaf(c, b.y, -s * a.x);
          }
        } else {
          constexpr int cl = 1 << PC;
          bool ct = (lane & cl) != 0;
          C2 a = v[r], b = v[r | tm];
          float nax = fmaf(c, a.x,  s * b.y);
          float nay = fmaf(c, a.y, -s * b.x);
          float nbx = fmaf(c, b.x,  s * a.y);
          float nby = fmaf(c, b.y, -s * a.x);
          v[r].x      = ct ? nax : a.x;
          v[r].y      = ct ? nay : a.y;
          v[r | tm].x = ct ? nbx : b.x;
          v[r | tm].y = ct ? nby : b.y;
        }
      }
    }
  } else {
    constexpr int tm = 1 << PT;
#pragma unroll
    for (int r = 0; r < 16; ++r) {
      if constexpr (PC >= 6) {
        constexpr int cm = 1 << (PC - 6);
        if ((r & cm) == 0) continue;
      }
      float px = __shfl_xor(v[r].x, tm, 64);
      float py = __shfl_xor(v[r].y, tm, 64);
      float nx = fmaf(c, v[r].x,  s * py);
      float ny = fmaf(c, v[r].y, -s * px);
      if constexpr (PC >= 6) {
        v[r].x = nx; v[r].y = ny;
      } else {
        constexpr int cl = 1 << PC;
        bool ct = (lane & cl) != 0;
        v[r].x = ct ? nx : v[r].x;
        v[r].y = ct ? ny : v[r].y;
      }
    }
  }
}

#define RYG(w, g)       ry_gate<9-(w)>(v, lane, cs[2*(g)], cs[2*(g)+1])
#define CRXG(cw, tw, g) crx_gate<9-(cw), 9-(tw)>(v, lane, cs[2*(g)], cs[2*(g)+1])

DEV void apply_layer(C2 v[16], int lane, const float* __restrict__ cs) {
  RYG(0,0); RYG(1,1); RYG(2,2); RYG(3,3); RYG(4,4);
  RYG(5,5); RYG(6,6); RYG(7,7); RYG(8,8); RYG(9,9);
  CRXG(9,0,10); CRXG(8,9,11); CRXG(7,8,12); CRXG(6,7,13); CRXG(5,6,14);
  CRXG(4,5,15); CRXG(3,4,16); CRXG(2,3,17); CRXG(1,2,18); CRXG(0,1,19);
  RYG(0,20); RYG(1,21); RYG(2,22); RYG(3,23); RYG(4,24);
  RYG(5,25); RYG(6,26); RYG(7,27); RYG(8,28); RYG(9,29);
  CRXG(9,8,30); CRXG(0,9,31); CRXG(1,0,32); CRXG(2,1,33); CRXG(3,2,34);
  CRXG(4,3,35); CRXG(5,4,36); CRXG(6,5,37); CRXG(7,6,38); CRXG(8,7,39);
}

template<int P>
DEV void measure_wire(const C2 v[16], int lane, float* ev, int w) {
  float x = 0.f, y = 0.f, z = 0.f;
  if constexpr (P >= 6) {
    constexpr int rm = 1 << (P - 6);
#pragma unroll
    for (int r = 0; r < 16; ++r) {
      if ((r & rm) == 0) {
        C2 a = v[r], b = v[r | rm];
        x += a.x*b.x + a.y*b.y;
        y += a.x*b.y - a.y*b.x;
        z += (a.x*a.x + a.y*a.y) - (b.x*b.x + b.y*b.y);
      }
    }
  } else {
    constexpr int lm = 1 << P;
#pragma unroll
    for (int r = 0; r < 16; ++r) {
      float px = __shfl_xor(v[r].x, lm, 64);
      float py = __shfl_xor(v[r].y, lm, 64);
      if ((lane & lm) == 0) {
        C2 a = v[r];
        x += a.x*px + a.y*py;
        y += a.x*py - a.y*px;
        z += (a.x*a.x + a.y*a.y) - (px*px + py*py);
      }
    }
  }
  for (int s = 1; s < 64; s <<= 1) {
    x += __shfl_xor(x, s, 64);
    y += __shfl_xor(y, s, 64);
    z += __shfl_xor(z, s, 64);
  }
  if (lane == 0) {
    ev[w]      = 2.f * x;
    ev[10 + w] = 2.f * y;
    ev[20 + w] = z;
  }
}

DEV void measure_all(const C2 v[16], int lane, float* ev) {
  measure_wire<9>(v, lane, ev, 0);
  measure_wire<8>(v, lane, ev, 1);
  measure_wire<7>(v, lane, ev, 2);
  measure_wire<6>(v, lane, ev, 3);
  measure_wire<5>(v, lane, ev, 4);
  measure_wire<4>(v, lane, ev, 5);
  measure_wire<3>(v, lane, ev, 6);
  measure_wire<2>(v, lane, ev, 7);
  measure_wire<1>(v, lane, ev, 8);
  measure_wire<0>(v, lane, ev, 9);
}

// ================= the single cooperative mega-kernel =================
// 256 blocks x 256 threads, all phases separated by grid.sync().
// Block g owns tokens/states 4g..4g+3 (wave wid -> state 4g+wid).
__global__ __launch_bounds__(256) void k_mega(
    const int* __restrict__ x, const float* __restrict__ emb,
    const float* __restrict__ w_ang, const float* __restrict__ b_ang,
    const float* __restrict__ coef, const float* __restrict__ lr,
    const float* __restrict__ li, const float* __restrict__ qff,
    const float* __restrict__ w1, const float* __restrict__ b1,
    const float* __restrict__ w2, const float* __restrict__ b2,
    float* __restrict__ out, float* __restrict__ ws) {
  cg::grid_group grid = cg::this_grid();

  __shared__ float4 hT[4096];        // 64KB: phase A emb staging; phase F h tile
  __shared__ float  cs_lds[4][160];  // per-wave-token gate (cos,sin), lives A..B3
  __shared__ float  qff_lds[80];     // phase D

  const int tid  = threadIdx.x;
  const int g    = blockIdx.x;
  const int wid  = tid >> 6;
  const int lane = tid & 63;

  // ---- lcu into registers (per wave; cheap, no cross-block dependency) ----
  float lre_v = 0.f, lim_v = 0.f;
  if (lane < 32) { lre_v = lr[lane]; lim_v = li[lane]; }
  float ab = sqrtf(lre_v * lre_v + lim_v * lim_v);
  for (int s = 1; s < 64; s <<= 1) ab += __shfl_xor(ab, s, 64);
  const float invL = 1.f / fmaxf(ab, 1e-12f);
  const int state  = g * 4 + wid;
  const int sb     = state >> 5;      // batch
  const int stok   = state & 31;      // token
  const float wre = __shfl(lre_v, stok, 64) * invL;
  const float wim = __shfl(lim_v, stok, 64) * invL;

  // ---- phase A: angles for this block's 4 tokens -> cs_lds ----
  {
    float* e4 = (float*)hT;          // [4][512]
    int tok = g * 4 + wid;
    int row = x[tok];
    const float4* er = (const float4*)(emb + (size_t)row * 512);
    float4* dst = (float4*)(e4 + wid * 512);
    dst[lane]      = er[lane];
    dst[lane + 64] = er[lane + 64];
    __syncthreads();
    if (tid < 80) {
      const float4* wr = (const float4*)(w_ang + (size_t)tid * 512);
      float bv = b_ang[tid];
      float a0 = bv, a1 = bv, a2 = bv, a3 = bv;
      const float4* e0p = (const float4*)(e4);
      const float4* e1p = (const float4*)(e4 + 512);
      const float4* e2p = (const float4*)(e4 + 1024);
      const float4* e3p = (const float4*)(e4 + 1536);
#pragma unroll 4
      for (int j = 0; j < 128; ++j) {
        float4 w4 = wr[j];
        float4 e0 = e0p[j], e1 = e1p[j], e2 = e2p[j], e3 = e3p[j];
        a0 = fmaf(w4.x, e0.x, a0); a0 = fmaf(w4.y, e0.y, a0);
        a0 = fmaf(w4.z, e0.z, a0); a0 = fmaf(w4.w, e0.w, a0);
        a1 = fmaf(w4.x, e1.x, a1); a1 = fmaf(w4.y, e1.y, a1);
        a1 = fmaf(w4.z, e1.z, a1); a1 = fmaf(w4.w, e1.w, a1);
        a2 = fmaf(w4.x, e2.x, a2); a2 = fmaf(w4.y, e2.y, a2);
        a2 = fmaf(w4.z, e2.z, a2); a2 = fmaf(w4.w, e2.w, a2);
        a3 = fmaf(w4.x, e3.x, a3); a3 = fmaf(w4.y, e3.y, a3);
        a3 = fmaf(w4.z, e3.z, a3); a3 = fmaf(w4.w, e3.w, a3);
      }
      cs_lds[0][2*tid] = cosf(0.5f*a0); cs_lds[0][2*tid+1] = sinf(0.5f*a0);
      cs_lds[1][2*tid] = cosf(0.5f*a1); cs_lds[1][2*tid+1] = sinf(0.5f*a1);
      cs_lds[2][2*tid] = cosf(0.5f*a2); cs_lds[2][2*tid+1] = sinf(0.5f*a2);
      cs_lds[3][2*tid] = cosf(0.5f*a3); cs_lds[3][2*tid+1] = sinf(0.5f*a3);
    }
    __syncthreads();
  }

  // ---- QSVT iterations: evolve (B) + reduce (C), acc in registers ----
  float2* const monog = (float2*)(ws + OFF_MONO);
  float2* const accg  = (float2*)(ws + OFF_ACC);
  float2* const stg   = (float2*)(ws + OFF_ST);
  float acc_x = 0.f, acc_y = 0.f;

#pragma unroll 1
  for (int k = 1; k <= 3; ++k) {
    // phase B_k: evolve state 4g+wid
    {
      C2 v[16];
      if (k == 1) {
#pragma unroll
        for (int r = 0; r < 16; ++r) {
          v[r].x = (r == 0 && lane == 0) ? 1.f : 0.f;
          v[r].y = 0.f;
        }
      } else {
        const float2* mono = monog + (size_t)sb * 1024;
#pragma unroll
        for (int r = 0; r < 16; ++r) {
          float2 m = mono[(r << 6) | lane];
          v[r].x = m.x; v[r].y = m.y;
        }
      }
      const float* cs0 = cs_lds[wid];
      apply_layer(v, lane, cs0);
      apply_layer(v, lane, cs0 + 80);
      float2* stp = stg + (size_t)state * 1024;
#pragma unroll
      for (int r = 0; r < 16; ++r) {
        stp[(r << 6) | lane] = make_float2(wre * v[r].x - wim * v[r].y,
                                           wre * v[r].y + wim * v[r].x);
      }
    }
    grid.sync();

    // phase C_k: reduce over tokens; acc stays in registers
    {
      int idx = g * 256 + tid;
      if (idx < 32768) {
        int b = idx >> 10, i = idx & 1023;
        const float2* st = stg + (size_t)b * 32768 + i;
        float sx = 0.f, sy = 0.f;
#pragma unroll
        for (int t = 0; t < 32; ++t) {
          float2 vv = st[t * 1024];
          sx += vv.x; sy += vv.y;
        }
        float ck = coef[k];
        if (k == 1) {
          float e0 = (i == 0) ? coef[0] : 0.f;
          acc_x = e0 + ck * sx;
          acc_y = ck * sy;
        } else {
          acc_x = fmaf(ck, sx, acc_x);
          acc_y = fmaf(ck, sy, acc_y);
        }
        if (k < 3) {
          monog[idx] = make_float2(sx, sy);
        } else {
          accg[idx] = make_float2(acc_x, acc_y);
        }
      }
    }
    grid.sync();
  }

  // ---- phase D: final circuit + measurement (blocks 0..31, wave 0) ----
  if (g < 32) {
    if (tid < 40) {
      float th = 0.5f * qff[tid];
      qff_lds[2*tid]     = cosf(th);
      qff_lds[2*tid + 1] = sinf(th);
    }
    __syncthreads();
    if (wid == 0) {
      float den = fabsf(coef[0]) + fabsf(coef[1]) + fabsf(coef[2]) + fabsf(coef[3]);
      float invd = 1.f / den;
      const float2* accp = accg + (size_t)g * 1024;
      C2 v[16];
      float ssum = 0.f;
#pragma unroll
      for (int r = 0; r < 16; ++r) {
        float2 m = accp[(r << 6) | lane];
        v[r].x = m.x * invd; v[r].y = m.y * invd;
        ssum += v[r].x * v[r].x + v[r].y * v[r].y;
      }
      for (int s = 1; s < 64; s <<= 1) ssum += __shfl_xor(ssum, s, 64);
      float nrm = sqrtf(ssum);
      if (lane == 0) ws[OFF_NRM + g] = nrm;
      float sc = 1.f / fmaxf(nrm, 1e-12f);
#pragma unroll
      for (int r = 0; r < 16; ++r) { v[r].x *= sc; v[r].y *= sc; }
      apply_layer(v, lane, qff_lds);
      measure_all(v, lane, ws + OFF_EV + g * 30);
    }
  }
  grid.sync();

  // ---- phase E: h = relu(ev @ w1.T + b1); mean(norm) ----
  {
    int idx = g * 256 + tid;
    if (idx < 16384) {
      int b = idx >> 9, j = idx & 511;
      const float* ev = ws + OFF_EV + b * 30;
      const float* wr = w1 + (size_t)j * 30;
      float a = b1[j];
#pragma unroll
      for (int q = 0; q < 30; ++q) a = fmaf(ev[q], wr[q], a);
      ws[OFF_H + idx] = fmaxf(a, 0.f);
    }
    if (idx == 0) {
      float s = 0.f;
      for (int i = 0; i < 32; ++i) s += ws[OFF_NRM + i];
      out[32000u * 32u] = s * (1.f / 32.f);
    }
  }
  grid.sync();

  // ---- phase F: logits = h @ w2.T + b2 (blocks 0..249) ----
  if (g < 250) {
    const float4* hg = (const float4*)(ws + OFF_H);   // [32][128] f4
#pragma unroll
    for (int p = 0; p < 16; ++p) {
      int idx = tid + p * 256;
      int m = idx >> 7, kf4 = idx & 127;
      hT[m * 128 + (kf4 ^ (m >> 3))] = hg[idx];
    }
    __syncthreads();

    int wv = wid;
    int mg = lane & 3, nl = lane >> 2;
    int nbase = g * 128;
    float acc[8][8];   // [j][mi]
#pragma unroll
    for (int j = 0; j < 8; ++j)
#pragma unroll
      for (int mi = 0; mi < 8; ++mi) acc[j][mi] = 0.f;

    const float* wbase = w2 + (size_t)(nbase + nl * 8) * 512 + wv * 128;
    int kqb = wv * 32;
    for (int kf4 = 0; kf4 < 32; ++kf4) {
      int kcol = kqb + kf4;
      float4 h4[8];
#pragma unroll
      for (int mi = 0; mi < 8; ++mi) {
        int m = mg * 8 + mi;
        h4[mi] = hT[m * 128 + (kcol ^ mg)];
      }
#pragma unroll
      for (int j = 0; j < 8; ++j) {
        float4 w4 = *(const float4*)(wbase + (size_t)j * 512 + kf4 * 4);
#pragma unroll
        for (int mi = 0; mi < 8; ++mi) {
          acc[j][mi] = fmaf(w4.x, h4[mi].x, acc[j][mi]);
          acc[j][mi] = fmaf(w4.y, h4[mi].y, acc[j][mi]);
          acc[j][mi] = fmaf(w4.z, h4[mi].z, acc[j][mi]);
          acc[j][mi] = fmaf(w4.w, h4[mi].w, acc[j][mi]);
        }
      }
    }

    __syncthreads();
    if (wv != 0) {
      int r = wv - 1;
      float4* cb = hT + r * 1024 + lane * 16;
#pragma unroll
      for (int mi = 0; mi < 8; ++mi) {
#pragma unroll
        for (int jh = 0; jh < 2; ++jh) {
          int q = mi * 2 + jh;
          float4 vv = make_float4(acc[jh*4+0][mi], acc[jh*4+1][mi],
                                  acc[jh*4+2][mi], acc[jh*4+3][mi]);
          cb[q ^ (lane & 15)] = vv;
        }
      }
    }
    __syncthreads();
    if (wv == 0) {
#pragma unroll
      for (int r = 0; r < 3; ++r) {
        const float4* cb = hT + r * 1024 + lane * 16;
#pragma unroll
        for (int mi = 0; mi < 8; ++mi) {
#pragma unroll
          for (int jh = 0; jh < 2; ++jh) {
            int q = mi * 2 + jh;
            float4 vv = cb[q ^ (lane & 15)];
            acc[jh*4+0][mi] += vv.x;
            acc[jh*4+1][mi] += vv.y;
            acc[jh*4+2][mi] += vv.z;
            acc[jh*4+3][mi] += vv.w;
          }
        }
      }
      float4 b2lo = *(const float4*)(b2 + nbase + nl * 8);
      float4 b2hi = *(const float4*)(b2 + nbase + nl * 8 + 4);
#pragma unroll
      for (int mi = 0; mi < 8; ++mi) {
        int m = mg * 8 + mi;
        float* orow = out + (size_t)m * 32000 + nbase + nl * 8;
        float4 lo = make_float4(acc[0][mi] + b2lo.x, acc[1][mi] + b2lo.y,
                                acc[2][mi] + b2lo.z, acc[3][mi] + b2lo.w);
        float4 hi = make_float4(acc[4][mi] + b2hi.x, acc[5][mi] + b2hi.y,
                                acc[6][mi] + b2hi.z, acc[7][mi] + b2hi.w);
        *(float4*)(orow)     = lo;
        *(float4*)(orow + 4) = hi;
      }
    }
  }
}

}  // namespace

extern "C" void kernel_launch(void* const* d_in, const int* in_sizes, int n_in,
                              void* d_out, int out_size, void* d_ws, size_t ws_size,
                              hipStream_t stream) {
  (void)in_sizes; (void)n_in; (void)out_size; (void)ws_size;
  const int*   x    = (const int*)d_in[0];
  const float* emb  = (const float*)d_in[1];
  const float* wang = (const float*)d_in[2];
  const float* bang = (const float*)d_in[3];
  const float* coef = (const float*)d_in[4];
  const float* lre  = (const float*)d_in[5];
  const float* lim  = (const float*)d_in[6];
  const float* qff  = (const float*)d_in[7];
  const float* w1   = (const float*)d_in[8];
  const float* b1   = (const float*)d_in[9];
  const float* w2   = (const float*)d_in[10];
  const float* b2   = (const float*)d_in[11];
  float* out = (float*)d_out;
  float* ws  = (float*)d_ws;

  void* args[] = {(void*)&x,   (void*)&emb, (void*)&wang, (void*)&bang,
                  (void*)&coef, (void*)&lre, (void*)&lim,  (void*)&qff,
                  (void*)&w1,  (void*)&b1,  (void*)&w2,   (void*)&b2,
                  (void*)&out, (void*)&ws};
  hipLaunchCooperativeKernel((void*)k_mega, dim3(256), dim3(256), args, 0, stream);
}

// Round 4
// 164.003 us; speedup vs baseline: 2.3587x; 2.3587x over previous
//
#include <hip/hip_runtime.h>
#include <math.h>

#define DEV __device__ __forceinline__

namespace {

struct C2 { float x, y; };

// ---------------- workspace layout (float offsets) ----------------
constexpr size_t OFF_CS   = 0;        // 1024 tokens * 80 gates * 2 (cos,sin)  = 163840
constexpr size_t OFF_NRM  = 163988;   // 32
constexpr size_t OFF_MONO = 164096;   // 32*1024*float2 = 65536
constexpr size_t OFF_ACC  = 229632;   // 65536
constexpr size_t OFF_ST   = 295168;   // 1024*1024*float2 = 2097152
constexpr size_t OFF_H    = 2393280;  // 32*512

// ---------------- gate primitives ----------------
// amplitude index i = (reg<<6) | lane ; wire w lives at bit position P = 9 - w.

template<int P>
DEV void ry_gate(C2 v[16], int lane, float c, float s) {
  if constexpr (P >= 6) {
    constexpr int rm = 1 << (P - 6);
#pragma unroll
    for (int r = 0; r < 16; ++r) {
      if ((r & rm) == 0) {
        C2 a = v[r], b = v[r | rm];
        v[r].x      = fmaf(c, a.x, -s * b.x);
        v[r].y      = fmaf(c, a.y, -s * b.y);
        v[r | rm].x = fmaf(s, a.x,  c * b.x);
        v[r | rm].y = fmaf(s, a.y,  c * b.y);
      }
    }
  } else {
    constexpr int lm = 1 << P;
    float sg = (lane & lm) ? s : -s;
#pragma unroll
    for (int r = 0; r < 16; ++r) {
      float px = __shfl_xor(v[r].x, lm, 64);
      float py = __shfl_xor(v[r].y, lm, 64);
      v[r].x = fmaf(c, v[r].x, sg * px);
      v[r].y = fmaf(c, v[r].y, sg * py);
    }
  }
}

template<int PC, int PT>
DEV void crx_gate(C2 v[16], int lane, float c, float s) {
  if constexpr (PT >= 6) {
    constexpr int tm = 1 << (PT - 6);
#pragma unroll
    for (int r = 0; r < 16; ++r) {
      if ((r & tm) == 0) {
        if constexpr (PC >= 6) {
          constexpr int cm = 1 << (PC - 6);
          if ((r & cm) != 0) {
            C2 a = v[r], b = v[r | tm];
            v[r].x      = fmaf(c, a.x,  s * b.y);
            v[r].y      = fmaf(c, a.y, -s * b.x);
            v[r | tm].x = fmaf(c, b.x,  s * a.y);
            v[r | tm].y = fmaf(c, b.y, -s * a.x);
          }
        } else {
          constexpr int cl = 1 << PC;
          bool ct = (lane & cl) != 0;
          C2 a = v[r], b = v[r | tm];
          float nax = fmaf(c, a.x,  s * b.y);
          float nay = fmaf(c, a.y, -s * b.x);
          float nbx = fmaf(c, b.x,  s * a.y);
          float nby = fmaf(c, b.y, -s * a.x);
          v[r].x      = ct ? nax : a.x;
          v[r].y      = ct ? nay : a.y;
          v[r | tm].x = ct ? nbx : b.x;
          v[r | tm].y = ct ? nby : b.y;
        }
      }
    }
  } else {
    constexpr int tm = 1 << PT;
#pragma unroll
    for (int r = 0; r < 16; ++r) {
      if constexpr (PC >= 6) {
        constexpr int cm = 1 << (PC - 6);
        if ((r & cm) == 0) continue;
      }
      float px = __shfl_xor(v[r].x, tm, 64);
      float py = __shfl_xor(v[r].y, tm, 64);
      float nx = fmaf(c, v[r].x,  s * py);
      float ny = fmaf(c, v[r].y, -s * px);
      if constexpr (PC >= 6) {
        v[r].x = nx; v[r].y = ny;
      } else {
        constexpr int cl = 1 << PC;
        bool ct = (lane & cl) != 0;
        v[r].x = ct ? nx : v[r].x;
        v[r].y = ct ? ny : v[r].y;
      }
    }
  }
}

#define RYG(w, g)       ry_gate<9-(w)>(v, lane, cs[2*(g)], cs[2*(g)+1])
#define CRXG(cw, tw, g) crx_gate<9-(cw), 9-(tw)>(v, lane, cs[2*(g)], cs[2*(g)+1])

DEV void apply_layer(C2 v[16], int lane, const float* __restrict__ cs) {
  RYG(0,0); RYG(1,1); RYG(2,2); RYG(3,3); RYG(4,4);
  RYG(5,5); RYG(6,6); RYG(7,7); RYG(8,8); RYG(9,9);
  CRXG(9,0,10); CRXG(8,9,11); CRXG(7,8,12); CRXG(6,7,13); CRXG(5,6,14);
  CRXG(4,5,15); CRXG(3,4,16); CRXG(2,3,17); CRXG(1,2,18); CRXG(0,1,19);
  RYG(0,20); RYG(1,21); RYG(2,22); RYG(3,23); RYG(4,24);
  RYG(5,25); RYG(6,26); RYG(7,27); RYG(8,28); RYG(9,29);
  CRXG(9,8,30); CRXG(0,9,31); CRXG(1,0,32); CRXG(2,1,33); CRXG(3,2,34);
  CRXG(4,3,35); CRXG(5,4,36); CRXG(6,5,37); CRXG(7,6,38); CRXG(8,7,39);
}

template<int P>
DEV void measure_wire(const C2 v[16], int lane, float* ev, int w) {
  float x = 0.f, y = 0.f, z = 0.f;
  if constexpr (P >= 6) {
    constexpr int rm = 1 << (P - 6);
#pragma unroll
    for (int r = 0; r < 16; ++r) {
      if ((r & rm) == 0) {
        C2 a = v[r], b = v[r | rm];
        x += a.x*b.x + a.y*b.y;
        y += a.x*b.y - a.y*b.x;
        z += (a.x*a.x + a.y*a.y) - (b.x*b.x + b.y*b.y);
      }
    }
  } else {
    constexpr int lm = 1 << P;
#pragma unroll
    for (int r = 0; r < 16; ++r) {
      float px = __shfl_xor(v[r].x, lm, 64);
      float py = __shfl_xor(v[r].y, lm, 64);
      if ((lane & lm) == 0) {
        C2 a = v[r];
        x += a.x*px + a.y*py;
        y += a.x*py - a.y*px;
        z += (a.x*a.x + a.y*a.y) - (px*px + py*py);
      }
    }
  }
  for (int s = 1; s < 64; s <<= 1) {
    x += __shfl_xor(x, s, 64);
    y += __shfl_xor(y, s, 64);
    z += __shfl_xor(z, s, 64);
  }
  if (lane == 0) {
    ev[w]      = 2.f * x;
    ev[10 + w] = 2.f * y;
    ev[20 + w] = z;
  }
}

DEV void measure_all(const C2 v[16], int lane, float* ev) {
  measure_wire<9>(v, lane, ev, 0);
  measure_wire<8>(v, lane, ev, 1);
  measure_wire<7>(v, lane, ev, 2);
  measure_wire<6>(v, lane, ev, 3);
  measure_wire<5>(v, lane, ev, 4);
  measure_wire<4>(v, lane, ev, 5);
  measure_wire<3>(v, lane, ev, 6);
  measure_wire<2>(v, lane, ev, 7);
  measure_wire<1>(v, lane, ev, 8);
  measure_wire<0>(v, lane, ev, 9);
}

// ---------------- kernels ----------------

// K1: angles for 2 tokens per block. 512 blocks x 128.
__global__ __launch_bounds__(128) void k_angles(const int* __restrict__ x,
                                                const float* __restrict__ emb,
                                                const float* __restrict__ w_ang,
                                                const float* __restrict__ b_ang,
                                                float* __restrict__ ws) {
  __shared__ float4 e2[2][128];
  int g = blockIdx.x;
  int tid = threadIdx.x;
  int r0 = x[2 * g], r1 = x[2 * g + 1];
  e2[0][tid] = ((const float4*)(emb + (size_t)r0 * 512))[tid];
  e2[1][tid] = ((const float4*)(emb + (size_t)r1 * 512))[tid];
  __syncthreads();
  if (tid < 80) {
    const float4* wr = (const float4*)(w_ang + (size_t)tid * 512);
    float bv = b_ang[tid];
    float a0 = bv, a1 = bv;
#pragma unroll 4
    for (int j = 0; j < 128; ++j) {
      float4 w = wr[j];
      float4 e0 = e2[0][j], e1 = e2[1][j];
      a0 = fmaf(w.x, e0.x, a0); a0 = fmaf(w.y, e0.y, a0);
      a0 = fmaf(w.z, e0.z, a0); a0 = fmaf(w.w, e0.w, a0);
      a1 = fmaf(w.x, e1.x, a1); a1 = fmaf(w.y, e1.y, a1);
      a1 = fmaf(w.z, e1.z, a1); a1 = fmaf(w.w, e1.w, a1);
    }
    float t0 = 0.5f * a0, t1 = 0.5f * a1;
    ws[OFF_CS + (size_t)(2 * g) * 160 + 2 * tid]         = cosf(t0);
    ws[OFF_CS + (size_t)(2 * g) * 160 + 2 * tid + 1]     = sinf(t0);
    ws[OFF_CS + (size_t)(2 * g + 1) * 160 + 2 * tid]     = cosf(t1);
    ws[OFF_CS + (size_t)(2 * g + 1) * 160 + 2 * tid + 1] = sinf(t1);
  }
}

// K2: evolve. one wave per (b,t) state. k==1 builds |0> in regs (no init kernel).
__global__ __launch_bounds__(256) void k_evolve(float* __restrict__ ws,
                                                const float* __restrict__ lr,
                                                const float* __restrict__ li,
                                                int k) {
  __shared__ float cs_lds[640];
  int tid = threadIdx.x;
  const float* csg = ws + OFF_CS + (size_t)blockIdx.x * 640;
  for (int i = tid; i < 640; i += 256) cs_lds[i] = csg[i];
  __syncthreads();
  int wid = tid >> 6, lane = tid & 63;
  int state = blockIdx.x * 4 + wid;
  int b = state >> 5, t = state & 31;

  // lcu weight for this token (normalize in-register; cheap, wave-uniform)
  float lre_v = 0.f, lim_v = 0.f;
  if (lane < 32) { lre_v = lr[lane]; lim_v = li[lane]; }
  float ab = sqrtf(lre_v * lre_v + lim_v * lim_v);
  for (int s = 1; s < 64; s <<= 1) ab += __shfl_xor(ab, s, 64);
  float invL = 1.f / fmaxf(ab, 1e-12f);
  float wre = __shfl(lre_v, t, 64) * invL;
  float wim = __shfl(lim_v, t, 64) * invL;

  C2 v[16];
  if (k == 1) {
#pragma unroll
    for (int r = 0; r < 16; ++r) {
      v[r].x = (r == 0 && lane == 0) ? 1.f : 0.f;
      v[r].y = 0.f;
    }
  } else {
    const float2* mono = (const float2*)(ws + OFF_MONO) + (size_t)b * 1024;
#pragma unroll
    for (int r = 0; r < 16; ++r) {
      float2 m = mono[(r << 6) | lane];
      v[r].x = m.x; v[r].y = m.y;
    }
  }
  const float* csw = &cs_lds[wid * 160];
  apply_layer(v, lane, csw);
  apply_layer(v, lane, csw + 80);
  float2* st = (float2*)(ws + OFF_ST) + (size_t)state * 1024;
#pragma unroll
  for (int r = 0; r < 16; ++r) {
    st[(r << 6) | lane] = make_float2(wre * v[r].x - wim * v[r].y,
                                      wre * v[r].y + wim * v[r].x);
  }
}

// K3: mono[b] = sum_t st[b,t]; acc accumulation. 128x256.
// k==1: acc = (i==0?c0:0) + c1*s  (no init kernel needed)
// k==2: acc += c2*s ; k==3: acc += c3*s (and skip mono write)
__global__ void k_reduce(float* __restrict__ ws, const float* __restrict__ coef, int k) {
  int idx = blockIdx.x * 256 + threadIdx.x;
  int b = idx >> 10, i = idx & 1023;
  const float2* st = (const float2*)(ws + OFF_ST) + (size_t)b * 32768 + i;
  float sx = 0.f, sy = 0.f;
#pragma unroll
  for (int t = 0; t < 32; ++t) {
    float2 vv = st[t * 1024];
    sx += vv.x; sy += vv.y;
  }
  float2* mono = (float2*)(ws + OFF_MONO);
  float2* acc  = (float2*)(ws + OFF_ACC);
  float ck = coef[k];
  if (k == 1) {
    float e0 = (i == 0) ? coef[0] : 0.f;
    acc[idx] = make_float2(fmaf(ck, sx, e0), ck * sy);
    mono[idx] = make_float2(sx, sy);
  } else {
    float2 a = acc[idx];
    a.x = fmaf(ck, sx, a.x);
    a.y = fmaf(ck, sy, a.y);
    acc[idx] = a;
    if (k < 3) mono[idx] = make_float2(sx, sy);
  }
}

// K5: final circuit + measure (wave 0) then fused mlp1 (all 4 waves). 32 blocks x 256.
__global__ __launch_bounds__(256) void k_final(float* __restrict__ ws,
                                               const float* __restrict__ coef,
                                               const float* __restrict__ qff,
                                               const float* __restrict__ w1,
                                               const float* __restrict__ b1) {
  __shared__ float qff_lds[80];
  __shared__ float ev_lds[30];
  int tid = threadIdx.x;
  int b = blockIdx.x;
  if (tid < 40) {
    float th = 0.5f * qff[tid];
    qff_lds[2 * tid]     = cosf(th);
    qff_lds[2 * tid + 1] = sinf(th);
  }
  __syncthreads();
  if (tid < 64) {
    int lane = tid;
    float den = fabsf(coef[0]) + fabsf(coef[1]) + fabsf(coef[2]) + fabsf(coef[3]);
    float invd = 1.f / den;
    const float2* accp = (const float2*)(ws + OFF_ACC) + (size_t)b * 1024;
    C2 v[16];
    float ssum = 0.f;
#pragma unroll
    for (int r = 0; r < 16; ++r) {
      float2 m = accp[(r << 6) | lane];
      v[r].x = m.x * invd; v[r].y = m.y * invd;
      ssum += v[r].x * v[r].x + v[r].y * v[r].y;
    }
    for (int s = 1; s < 64; s <<= 1) ssum += __shfl_xor(ssum, s, 64);
    float nrm = sqrtf(ssum);
    if (lane == 0) ws[OFF_NRM + b] = nrm;
    float sc = 1.f / fmaxf(nrm, 1e-12f);
#pragma unroll
    for (int r = 0; r < 16; ++r) { v[r].x *= sc; v[r].y *= sc; }
    apply_layer(v, lane, qff_lds);
    measure_all(v, lane, ev_lds);
  }
  __syncthreads();
  // fused mlp1: h[b][j] = relu(ev . w1[j] + b1[j]), j = tid and tid+256
#pragma unroll
  for (int jj = 0; jj < 2; ++jj) {
    int j = tid + jj * 256;
    const float* wr = w1 + (size_t)j * 30;
    float a = b1[j];
#pragma unroll
    for (int q = 0; q < 30; ++q) a = fmaf(ev_lds[q], wr[q], a);
    ws[OFF_H + b * 512 + j] = fmaxf(a, 0.f);
  }
}

// K7: logits = h @ w2.T + b2.  M=32, N=32000, K=512. (+ mean(norm) by block 0)
__global__ __launch_bounds__(256) void k_logits(const float* __restrict__ ws,
                                                const float* __restrict__ w2,
                                                const float* __restrict__ b2,
                                                float* __restrict__ out) {
  __shared__ float4 hT[4096];   // 64 KB
  int tid = threadIdx.x;
  if (blockIdx.x == 0 && tid == 0) {
    float s = 0.f;
    for (int i = 0; i < 32; ++i) s += ws[OFF_NRM + i];
    out[32000u * 32u] = s * (1.f / 32.f);
  }
  const float4* hg = (const float4*)(ws + OFF_H);   // [32][128] f4
#pragma unroll
  for (int p = 0; p < 16; ++p) {
    int idx = tid + p * 256;
    int m = idx >> 7, kf4 = idx & 127;
    hT[m * 128 + (kf4 ^ (m >> 3))] = hg[idx];
  }
  __syncthreads();

  int wv = tid >> 6, lane = tid & 63;
  int mg = lane & 3, nl = lane >> 2;
  int nbase = blockIdx.x * 128;
  float acc[8][8];   // [j][mi]
#pragma unroll
  for (int j = 0; j < 8; ++j)
#pragma unroll
    for (int mi = 0; mi < 8; ++mi) acc[j][mi] = 0.f;

  const float* wbase = w2 + (size_t)(nbase + nl * 8) * 512 + wv * 128;
  int kqb = wv * 32;
  for (int kf4 = 0; kf4 < 32; ++kf4) {
    int kcol = kqb + kf4;
    float4 h4[8];
#pragma unroll
    for (int mi = 0; mi < 8; ++mi) {
      int m = mg * 8 + mi;
      h4[mi] = hT[m * 128 + (kcol ^ mg)];
    }
#pragma unroll
    for (int j = 0; j < 8; ++j) {
      float4 w4 = *(const float4*)(wbase + (size_t)j * 512 + kf4 * 4);
#pragma unroll
      for (int mi = 0; mi < 8; ++mi) {
        acc[j][mi] = fmaf(w4.x, h4[mi].x, acc[j][mi]);
        acc[j][mi] = fmaf(w4.y, h4[mi].y, acc[j][mi]);
        acc[j][mi] = fmaf(w4.z, h4[mi].z, acc[j][mi]);
        acc[j][mi] = fmaf(w4.w, h4[mi].w, acc[j][mi]);
      }
    }
  }

  __syncthreads();
  if (wv != 0) {
    int r = wv - 1;
    float4* cb = hT + r * 1024 + lane * 16;
#pragma unroll
    for (int mi = 0; mi < 8; ++mi) {
#pragma unroll
      for (int jh = 0; jh < 2; ++jh) {
        int q = mi * 2 + jh;
        float4 vv = make_float4(acc[jh*4+0][mi], acc[jh*4+1][mi],
                                acc[jh*4+2][mi], acc[jh*4+3][mi]);
        cb[q ^ (lane & 15)] = vv;
      }
    }
  }
  __syncthreads();
  if (wv == 0) {
#pragma unroll
    for (int r = 0; r < 3; ++r) {
      const float4* cb = hT + r * 1024 + lane * 16;
#pragma unroll
      for (int mi = 0; mi < 8; ++mi) {
#pragma unroll
        for (int jh = 0; jh < 2; ++jh) {
          int q = mi * 2 + jh;
          float4 vv = cb[q ^ (lane & 15)];
          acc[jh*4+0][mi] += vv.x;
          acc[jh*4+1][mi] += vv.y;
          acc[jh*4+2][mi] += vv.z;
          acc[jh*4+3][mi] += vv.w;
        }
      }
    }
    float4 b2lo = *(const float4*)(b2 + nbase + nl * 8);
    float4 b2hi = *(const float4*)(b2 + nbase + nl * 8 + 4);
#pragma unroll
    for (int mi = 0; mi < 8; ++mi) {
      int m = mg * 8 + mi;
      float* orow = out + (size_t)m * 32000 + nbase + nl * 8;
      float4 lo = make_float4(acc[0][mi] + b2lo.x, acc[1][mi] + b2lo.y,
                              acc[2][mi] + b2lo.z, acc[3][mi] + b2lo.w);
      float4 hi = make_float4(acc[4][mi] + b2hi.x, acc[5][mi] + b2hi.y,
                              acc[6][mi] + b2hi.z, acc[7][mi] + b2hi.w);
      *(float4*)(orow)     = lo;
      *(float4*)(orow + 4) = hi;
    }
  }
}

}  // namespace

extern "C" void kernel_launch(void* const* d_in, const int* in_sizes, int n_in,
                              void* d_out, int out_size, void* d_ws, size_t ws_size,
                              hipStream_t stream) {
  (void)in_sizes; (void)n_in; (void)out_size; (void)ws_size;
  const int*   x    = (const int*)d_in[0];
  const float* emb  = (const float*)d_in[1];
  const float* wang = (const float*)d_in[2];
  const float* bang = (const float*)d_in[3];
  const float* coef = (const float*)d_in[4];
  const float* lre  = (const float*)d_in[5];
  const float* lim  = (const float*)d_in[6];
  const float* qff  = (const float*)d_in[7];
  const float* w1   = (const float*)d_in[8];
  const float* b1   = (const float*)d_in[9];
  const float* w2   = (const float*)d_in[10];
  const float* b2   = (const float*)d_in[11];
  float* out = (float*)d_out;
  float* ws  = (float*)d_ws;

  hipLaunchKernelGGL(k_angles, dim3(512), dim3(128), 0, stream, x, emb, wang, bang, ws);
  for (int k = 1; k <= 3; ++k) {
    hipLaunchKernelGGL(k_evolve, dim3(256), dim3(256), 0, stream, ws, lre, lim, k);
    hipLaunchKernelGGL(k_reduce, dim3(128), dim3(256), 0, stream, ws, coef, k);
  }
  hipLaunchKernelGGL(k_final,  dim3(32),  dim3(256), 0, stream, ws, coef, qff, w1, b1);
  hipLaunchKernelGGL(k_logits, dim3(250), dim3(256), 0, stream, ws, w2, b2, out);
}